// Round 1
// baseline (195.583 us; speedup 1.0000x reference)
//
#include <hip/hip_runtime.h>
#include <hip/hip_bf16.h>

#define DIM   128
#define NH    8
#define INNER 512
#define HD    64
#define BSZ   4
#define NSEQ  1024
#define PEC   32
#define BH    32   // BSZ*NH

typedef __attribute__((ext_vector_type(4))) float f32x4;
typedef __attribute__((ext_vector_type(8))) short s16x8;
typedef __attribute__((ext_vector_type(4))) unsigned short u16x4;

__device__ __forceinline__ unsigned short f2bf(float f) {
    unsigned u = __float_as_uint(f);
    u += 0x7fffu + ((u >> 16) & 1u);
    return (unsigned short)(u >> 16);
}

__device__ __forceinline__ s16x8 load8bf(const float* p) {
    f32x4 a = *(const f32x4*)p;
    f32x4 b = *(const f32x4*)(p + 4);
    s16x8 r;
    r[0] = (short)f2bf(a[0]); r[1] = (short)f2bf(a[1]);
    r[2] = (short)f2bf(a[2]); r[3] = (short)f2bf(a[3]);
    r[4] = (short)f2bf(b[0]); r[5] = (short)f2bf(b[1]);
    r[6] = (short)f2bf(b[2]); r[7] = (short)f2bf(b[3]);
    return r;
}

__device__ __forceinline__ f32x4 mfma16(s16x8 a, s16x8 b, f32x4 c) {
    return __builtin_amdgcn_mfma_f32_16x16x32_bf16(a, b, c, 0, 0, 0);
}

// ---------------------------------------------------------------------------
// K1: q/k/v projections.  q_ws,k_ws: bf16 [bh][n][d]  (q pre-scaled by 1/8)
//     vT_ws: bf16 [bh][d][n]  (transposed, bias added)
// grid (24, 256), block 256: each wave = one 16x16 output tile, K=128.
// ---------------------------------------------------------------------------
__global__ __launch_bounds__(256) void k_qkv(
    const float* __restrict__ x,
    const float* __restrict__ Wq, const float* __restrict__ Wk,
    const float* __restrict__ Wv, const float* __restrict__ bv,
    unsigned short* __restrict__ qws, unsigned short* __restrict__ kws,
    unsigned short* __restrict__ vtws)
{
    int lane = threadIdx.x & 63, wave = threadIdx.x >> 6;
    int lr = lane & 15, lg = lane >> 4;
    int ct   = blockIdx.x * 4 + wave;   // 0..95 column tile over 1536 cols
    int col0 = ct * 16;
    int m0   = blockIdx.y * 16;

    s16x8 a[4];
    const float* xrow = x + (m0 + lr) * DIM;
    #pragma unroll
    for (int kt = 0; kt < 4; ++kt) a[kt] = load8bf(xrow + kt * 32 + lg * 8);

    const float* W; int cbase; int which = col0 >> 9;
    if (which == 0)      { W = Wq; cbase = col0; }
    else if (which == 1) { W = Wk; cbase = col0 - 512; }
    else                 { W = Wv; cbase = col0 - 1024; }

    const float* wrow = W + (cbase + lr) * DIM;
    f32x4 acc = {0.f, 0.f, 0.f, 0.f};
    #pragma unroll
    for (int kt = 0; kt < 4; ++kt) {
        s16x8 bf = load8bf(wrow + kt * 32 + lg * 8);
        acc = mfma16(a[kt], bf, acc);
    }

    int colW = cbase + lr;          // 0..511 inside this projection
    int h = colW >> 6, d = colW & 63;
    int mB = m0 + lg * 4;           // 4 consecutive rows, same batch
    int b  = mB >> 10;
    int bh = b * NH + h;
    if (which == 2) {
        float bias = bv[colW];
        u16x4 pk;
        #pragma unroll
        for (int v = 0; v < 4; ++v) pk[v] = f2bf(acc[v] + bias);
        int n0 = mB & 1023;
        *(u16x4*)(vtws + (bh * HD + d) * NSEQ + n0) = pk;
    } else {
        #pragma unroll
        for (int v = 0; v < 4; ++v) {
            int n = (mB + v) & 1023;
            float val = acc[v];
            if (which == 0) qws[(bh * NSEQ + n) * HD + d] = f2bf(val * 0.125f);
            else            kws[(bh * NSEQ + n) * HD + d] = f2bf(val);
        }
    }
}

// ---------------------------------------------------------------------------
// K2: per (bh, 16 query rows): S = qk^T -> softmax (f32 LDS, XOR swizzle)
//     -> attn bf16 to ws [i][bh][j]  -> outv = P @ V (via vT)  f32 [bh][n][d]
// grid (64, 32), block 256.
// ---------------------------------------------------------------------------
__global__ __launch_bounds__(256) void k_attn(
    const unsigned short* __restrict__ qws, const unsigned short* __restrict__ kws,
    const unsigned short* __restrict__ vtws,
    unsigned short* __restrict__ attnw, float* __restrict__ outv)
{
    __shared__ char smem[16 * 1024 * 4];   // 64 KB, f32 [16][1024] XOR-swizzled
    int lane = threadIdx.x & 63, wave = threadIdx.x >> 6;
    int lr = lane & 15, lg = lane >> 4;
    int bh = blockIdx.y;
    int i0 = blockIdx.x * 16;

    auto sptr = [&](int r, int j) -> float* {
        unsigned byte = (unsigned)(r * 4096 + j * 4);
        byte ^= (unsigned)((r & 7) << 4);
        return (float*)(smem + byte);
    };

    // ---- phase 1: scores; wave w covers j in [w*256, w*256+256) ----
    s16x8 qf0, qf1;
    {
        const unsigned short* qrow = qws + (bh * NSEQ + i0 + lr) * HD;
        qf0 = *(const s16x8*)(qrow + lg * 8);
        qf1 = *(const s16x8*)(qrow + 32 + lg * 8);
    }
    for (int jt = 0; jt < 16; ++jt) {
        int j0 = (wave * 16 + jt) * 16;
        const unsigned short* krow = kws + (bh * NSEQ + j0 + lr) * HD;
        f32x4 acc = {0.f, 0.f, 0.f, 0.f};
        s16x8 b0 = *(const s16x8*)(krow + lg * 8);
        acc = mfma16(qf0, b0, acc);
        s16x8 b1 = *(const s16x8*)(krow + 32 + lg * 8);
        acc = mfma16(qf1, b1, acc);
        #pragma unroll
        for (int v = 0; v < 4; ++v) *sptr(lg * 4 + v, j0 + lr) = acc[v];
    }
    __syncthreads();

    // ---- phase 2: softmax. 16 threads per row (lane group), 8 elems/chunk ----
    int r   = threadIdx.x >> 4;
    int c16 = threadIdx.x & 15;
    float mx = -3.0e38f;
    #pragma unroll
    for (int it = 0; it < 8; ++it) {
        int j = it * 128 + c16 * 8;
        f32x4 a = *(f32x4*)sptr(r, j);
        f32x4 b = *(f32x4*)sptr(r, j + 4);
        mx = fmaxf(mx, fmaxf(fmaxf(fmaxf(a[0], a[1]), fmaxf(a[2], a[3])),
                             fmaxf(fmaxf(b[0], b[1]), fmaxf(b[2], b[3]))));
    }
    #pragma unroll
    for (int off = 8; off; off >>= 1) mx = fmaxf(mx, __shfl_xor(mx, off, 16));

    float sum = 0.f;
    #pragma unroll
    for (int it = 0; it < 8; ++it) {
        int j = it * 128 + c16 * 8;
        float* p0 = sptr(r, j);
        float* p1 = sptr(r, j + 4);
        f32x4 a = *(f32x4*)p0, b = *(f32x4*)p1;
        #pragma unroll
        for (int u = 0; u < 4; ++u) { a[u] = __expf(a[u] - mx); sum += a[u]; }
        #pragma unroll
        for (int u = 0; u < 4; ++u) { b[u] = __expf(b[u] - mx); sum += b[u]; }
        *(f32x4*)p0 = a; *(f32x4*)p1 = b;
    }
    #pragma unroll
    for (int off = 8; off; off >>= 1) sum += __shfl_xor(sum, off, 16);
    float inv = 1.0f / sum;

    unsigned short* arow = attnw + ((i0 + r) * BH + bh) * NSEQ;
    #pragma unroll
    for (int it = 0; it < 8; ++it) {
        int j = it * 128 + c16 * 8;
        float* p0 = sptr(r, j);
        float* p1 = sptr(r, j + 4);
        f32x4 a = *(f32x4*)p0, b = *(f32x4*)p1;
        s16x8 pk;
        #pragma unroll
        for (int u = 0; u < 4; ++u) { a[u] *= inv; pk[u]     = (short)f2bf(a[u]); }
        #pragma unroll
        for (int u = 0; u < 4; ++u) { b[u] *= inv; pk[4 + u] = (short)f2bf(b[u]); }
        *(f32x4*)p0 = a; *(f32x4*)p1 = b;
        *(s16x8*)(arow + j) = pk;
    }
    __syncthreads();

    // ---- phase 3: outv = P @ V ; wave w owns d quarter [w*16, w*16+16) ----
    int d0 = wave * 16;
    const unsigned short* vrow = vtws + (bh * HD + d0 + lr) * NSEQ;
    f32x4 oacc = {0.f, 0.f, 0.f, 0.f};
    for (int kt = 0; kt < 32; ++kt) {
        int jb = kt * 32 + lg * 8;
        f32x4 a0 = *(f32x4*)sptr(lr, jb);
        f32x4 a1 = *(f32x4*)sptr(lr, jb + 4);
        s16x8 af;
        af[0] = (short)f2bf(a0[0]); af[1] = (short)f2bf(a0[1]);
        af[2] = (short)f2bf(a0[2]); af[3] = (short)f2bf(a0[3]);
        af[4] = (short)f2bf(a1[0]); af[5] = (short)f2bf(a1[1]);
        af[6] = (short)f2bf(a1[2]); af[7] = (short)f2bf(a1[3]);
        s16x8 bf = *(const s16x8*)(vrow + jb);
        oacc = mfma16(af, bf, oacc);
    }
    float* orow = outv + (bh * NSEQ + i0) * HD;
    #pragma unroll
    for (int v = 0; v < 4; ++v)
        orow[(lg * 4 + v) * HD + d0 + lr] = oacc[v];
}

// ---------------------------------------------------------------------------
// K3: per query row i: pes[bh][i][c] = attn[i] (32bh x 1024j) @ pe[i] (1024j x 32c)
// grid (1024), block 256: 4 waves = 2 bh-halves x 2 c-halves.
// ---------------------------------------------------------------------------
__global__ __launch_bounds__(256) void k_pe(
    const unsigned short* __restrict__ attnw, const float* __restrict__ pe,
    float* __restrict__ pes)
{
    int i = blockIdx.x;
    int lane = threadIdx.x & 63, wave = threadIdx.x >> 6;
    int lr = lane & 15, lg = lane >> 4;
    int bh0 = (wave >> 1) * 16;
    int c0  = (wave & 1) * 16;
    const unsigned short* arow = attnw + (i * BH + bh0 + lr) * NSEQ;
    const float* pei = pe + (size_t)i * NSEQ * PEC;
    f32x4 acc = {0.f, 0.f, 0.f, 0.f};
    for (int kt = 0; kt < 32; ++kt) {
        int jb = kt * 32 + lg * 8;
        s16x8 af = *(const s16x8*)(arow + jb);
        s16x8 bf;
        #pragma unroll
        for (int ii = 0; ii < 8; ++ii)
            bf[ii] = (short)f2bf(pei[(jb + ii) * PEC + c0 + lr]);
        acc = mfma16(af, bf, acc);
    }
    #pragma unroll
    for (int v = 0; v < 4; ++v)
        pes[((bh0 + lg * 4 + v) * NSEQ + i) * PEC + c0 + lr] = acc[v];
}

// ---------------------------------------------------------------------------
// K4: t[b][n][h*64+d] = outv + pes @ Wpe^T + bpe   (bf16 packed)
// grid (32, 32), block 256: 32 rows/block, 8 threads/row, 8 d each.
// ---------------------------------------------------------------------------
__global__ __launch_bounds__(256) void k_comb(
    const float* __restrict__ outv, const float* __restrict__ pes,
    const float* __restrict__ Wpe, const float* __restrict__ bpe,
    unsigned short* __restrict__ tws)
{
    __shared__ float wpe_s[HD * PEC];
    __shared__ float bpe_s[HD];
    int tid = threadIdx.x;
    for (int idx = tid; idx < HD * PEC; idx += 256) wpe_s[idx] = Wpe[idx];
    if (tid < HD) bpe_s[tid] = bpe[tid];
    __syncthreads();

    int bh = blockIdx.y;
    int n  = blockIdx.x * 32 + (tid >> 3);
    int d0 = (tid & 7) * 8;
    int b = bh >> 3, h = bh & 7;

    float pr[PEC];
    const float* prow = pes + (bh * NSEQ + n) * PEC;
    #pragma unroll
    for (int c = 0; c < PEC; c += 4) {
        f32x4 t = *(const f32x4*)(prow + c);
        pr[c] = t[0]; pr[c + 1] = t[1]; pr[c + 2] = t[2]; pr[c + 3] = t[3];
    }
    const float* ovp = outv + (bh * NSEQ + n) * HD + d0;
    s16x8 pk;
    #pragma unroll
    for (int dd = 0; dd < 8; ++dd) {
        float acc = bpe_s[d0 + dd] + ovp[dd];
        const float* wrow = &wpe_s[(d0 + dd) * PEC];
        #pragma unroll
        for (int c = 0; c < PEC; ++c) acc += pr[c] * wrow[c];
        pk[dd] = (short)f2bf(acc);
    }
    *(s16x8*)(tws + (b * NSEQ + n) * INNER + h * HD + d0) = pk;
}

// ---------------------------------------------------------------------------
// K5: out[b][n][:] = t @ Wproj^T    (4096 x 128, K=512)
// grid (2, 256), block 256: each wave one 16x16 tile.
// ---------------------------------------------------------------------------
__global__ __launch_bounds__(256) void k_proj(
    const unsigned short* __restrict__ tws, const float* __restrict__ Wproj,
    float* __restrict__ out)
{
    int lane = threadIdx.x & 63, wave = threadIdx.x >> 6;
    int lr = lane & 15, lg = lane >> 4;
    int n0 = (blockIdx.x * 4 + wave) * 16;
    int m0 = blockIdx.y * 16;
    const unsigned short* arow = tws + (m0 + lr) * INNER;
    const float* brow = Wproj + (n0 + lr) * INNER;
    f32x4 acc = {0.f, 0.f, 0.f, 0.f};
    for (int kt = 0; kt < 16; ++kt) {
        s16x8 af = *(const s16x8*)(arow + kt * 32 + lg * 8);
        s16x8 bf = load8bf(brow + kt * 32 + lg * 8);
        acc = mfma16(af, bf, acc);
    }
    #pragma unroll
    for (int v = 0; v < 4; ++v)
        out[(m0 + lg * 4 + v) * DIM + n0 + lr] = acc[v];
}

// ---------------------------------------------------------------------------
// Workspace layout (92 MiB total):
//   [ 0,  4) MiB q_ws   bf16 [bh][n][64]
//   [ 4,  8) MiB k_ws   bf16 [bh][n][64]
//   [ 8, 12) MiB vT_ws  bf16 [bh][64][n]
//   [12, 76) MiB attn   bf16 [i][bh][j]
//   [76, 84) MiB outv   f32  [bh][n][64]
//   [84, 88) MiB pes    f32  [bh][n][32]
//   [88, 92) MiB t      bf16 [b][n][512]
// ---------------------------------------------------------------------------
extern "C" void kernel_launch(void* const* d_in, const int* in_sizes, int n_in,
                              void* d_out, int out_size, void* d_ws, size_t ws_size,
                              hipStream_t stream)
{
    const float* x     = (const float*)d_in[0];
    const float* pe    = (const float*)d_in[1];
    const float* Wq    = (const float*)d_in[2];
    const float* Wk    = (const float*)d_in[3];
    const float* Wv    = (const float*)d_in[4];
    const float* bv    = (const float*)d_in[5];
    const float* Wproj = (const float*)d_in[6];
    const float* Wpe   = (const float*)d_in[7];
    const float* bpe   = (const float*)d_in[8];
    float* out = (float*)d_out;

    char* ws = (char*)d_ws;
    unsigned short* qws  = (unsigned short*)(ws);
    unsigned short* kws  = (unsigned short*)(ws + ( 4u << 20));
    unsigned short* vtws = (unsigned short*)(ws + ( 8u << 20));
    unsigned short* attn = (unsigned short*)(ws + (12u << 20));
    float*          outv = (float*)         (ws + (76u << 20));
    float*          pes  = (float*)         (ws + (84u << 20));
    unsigned short* tws  = (unsigned short*)(ws + (88u << 20));

    k_qkv <<<dim3(24, 256), 256, 0, stream>>>(x, Wq, Wk, Wv, bv, qws, kws, vtws);
    k_attn<<<dim3(64, 32),  256, 0, stream>>>(qws, kws, vtws, attn, outv);
    k_pe  <<<dim3(1024),    256, 0, stream>>>(attn, pe, pes);
    k_comb<<<dim3(32, 32),  256, 0, stream>>>(outv, pes, Wpe, bpe, tws);
    k_proj<<<dim3(2, 256),  256, 0, stream>>>(tws, Wproj, out);
}

// Round 2
// 189.393 us; speedup vs baseline: 1.0327x; 1.0327x over previous
//
#include <hip/hip_runtime.h>
#include <hip/hip_bf16.h>

#define DIM   128
#define NH    8
#define INNER 512
#define HD    64
#define BSZ   4
#define NSEQ  1024
#define PEC   32
#define BH    32   // BSZ*NH

typedef __attribute__((ext_vector_type(4))) float f32x4;
typedef __attribute__((ext_vector_type(8))) short s16x8;
typedef __attribute__((ext_vector_type(4))) unsigned short u16x4;

__device__ __forceinline__ unsigned short f2bf(float f) {
    unsigned u = __float_as_uint(f);
    u += 0x7fffu + ((u >> 16) & 1u);
    return (unsigned short)(u >> 16);
}

__device__ __forceinline__ float bf2f(short s) {
    return __uint_as_float(((unsigned)(unsigned short)s) << 16);
}

__device__ __forceinline__ s16x8 load8bf(const float* p) {
    f32x4 a = *(const f32x4*)p;
    f32x4 b = *(const f32x4*)(p + 4);
    s16x8 r;
    r[0] = (short)f2bf(a[0]); r[1] = (short)f2bf(a[1]);
    r[2] = (short)f2bf(a[2]); r[3] = (short)f2bf(a[3]);
    r[4] = (short)f2bf(b[0]); r[5] = (short)f2bf(b[1]);
    r[6] = (short)f2bf(b[2]); r[7] = (short)f2bf(b[3]);
    return r;
}

__device__ __forceinline__ f32x4 mfma16(s16x8 a, s16x8 b, f32x4 c) {
    return __builtin_amdgcn_mfma_f32_16x16x32_bf16(a, b, c, 0, 0, 0);
}

// ---------------------------------------------------------------------------
// K1: q/k/v projections.  q_ws,k_ws: bf16 [bh][n][d]  (q pre-scaled by 1/8)
//     vT_ws: bf16 [bh][d][n]  (transposed, bias added)
// grid (24, 256), block 256: each wave = one 16x16 output tile, K=128.
// ---------------------------------------------------------------------------
__global__ __launch_bounds__(256) void k_qkv(
    const float* __restrict__ x,
    const float* __restrict__ Wq, const float* __restrict__ Wk,
    const float* __restrict__ Wv, const float* __restrict__ bv,
    unsigned short* __restrict__ qws, unsigned short* __restrict__ kws,
    unsigned short* __restrict__ vtws)
{
    int lane = threadIdx.x & 63, wave = threadIdx.x >> 6;
    int lr = lane & 15, lg = lane >> 4;
    int ct   = blockIdx.x * 4 + wave;   // 0..95 column tile over 1536 cols
    int col0 = ct * 16;
    int m0   = blockIdx.y * 16;

    s16x8 a[4];
    const float* xrow = x + (m0 + lr) * DIM;
    #pragma unroll
    for (int kt = 0; kt < 4; ++kt) a[kt] = load8bf(xrow + kt * 32 + lg * 8);

    const float* W; int cbase; int which = col0 >> 9;
    if (which == 0)      { W = Wq; cbase = col0; }
    else if (which == 1) { W = Wk; cbase = col0 - 512; }
    else                 { W = Wv; cbase = col0 - 1024; }

    const float* wrow = W + (cbase + lr) * DIM;
    f32x4 acc = {0.f, 0.f, 0.f, 0.f};
    #pragma unroll
    for (int kt = 0; kt < 4; ++kt) {
        s16x8 bf = load8bf(wrow + kt * 32 + lg * 8);
        acc = mfma16(a[kt], bf, acc);
    }

    int colW = cbase + lr;          // 0..511 inside this projection
    int h = colW >> 6, d = colW & 63;
    int mB = m0 + lg * 4;           // 4 consecutive rows, same batch
    int b  = mB >> 10;
    int bh = b * NH + h;
    if (which == 2) {
        float bias = bv[colW];
        u16x4 pk;
        #pragma unroll
        for (int v = 0; v < 4; ++v) pk[v] = f2bf(acc[v] + bias);
        int n0 = mB & 1023;
        *(u16x4*)(vtws + (bh * HD + d) * NSEQ + n0) = pk;
    } else {
        #pragma unroll
        for (int v = 0; v < 4; ++v) {
            int n = (mB + v) & 1023;
            float val = acc[v];
            if (which == 0) qws[(bh * NSEQ + n) * HD + d] = f2bf(val * 0.125f);
            else            kws[(bh * NSEQ + n) * HD + d] = f2bf(val);
        }
    }
}

// ---------------------------------------------------------------------------
// K2: per (bh, 16 query rows): S = qk^T -> softmax -> attn bf16 [i][bh][j]
//     -> outv = P @ V (via vT) f32 [bh][n][d]
// Scores held in 32 KB bf16 LDS (XOR swizzle) -> 5 blocks/CU occupancy.
// grid (64, 32), block 256.
// ---------------------------------------------------------------------------
__global__ __launch_bounds__(256) void k_attn(
    const unsigned short* __restrict__ qws, const unsigned short* __restrict__ kws,
    const unsigned short* __restrict__ vtws,
    unsigned short* __restrict__ attnw, float* __restrict__ outv)
{
    __shared__ unsigned short sS[16 * 1024];   // 32 KB bf16 [16][1024] swizzled
    int lane = threadIdx.x & 63, wave = threadIdx.x >> 6;
    int lr = lane & 15, lg = lane >> 4;
    int bh = blockIdx.y;
    int i0 = blockIdx.x * 16;

    auto sp = [&](int r, int j) -> unsigned short* {
        unsigned byte = (unsigned)(r * 2048 + j * 2);
        byte ^= (unsigned)((r & 7) << 4);
        return (unsigned short*)((char*)sS + byte);
    };

    // ---- phase 1: scores; wave w covers j in [w*256, w*256+256) ----
    s16x8 qf0, qf1;
    {
        const unsigned short* qrow = qws + (bh * NSEQ + i0 + lr) * HD;
        qf0 = *(const s16x8*)(qrow + lg * 8);
        qf1 = *(const s16x8*)(qrow + 32 + lg * 8);
    }
    for (int jt = 0; jt < 16; ++jt) {
        int j0 = (wave * 16 + jt) * 16;
        const unsigned short* krow = kws + (bh * NSEQ + j0 + lr) * HD;
        f32x4 acc = {0.f, 0.f, 0.f, 0.f};
        acc = mfma16(qf0, *(const s16x8*)(krow + lg * 8), acc);
        acc = mfma16(qf1, *(const s16x8*)(krow + 32 + lg * 8), acc);
        #pragma unroll
        for (int v = 0; v < 4; ++v) *sp(lg * 4 + v, j0 + lr) = f2bf(acc[v]);
    }
    __syncthreads();

    // ---- phase 2: softmax, 16 threads/row. pass A: max ----
    int r = threadIdx.x >> 4, c = threadIdx.x & 15;
    float mx = -3.0e38f;
    #pragma unroll
    for (int it = 0; it < 8; ++it) {
        s16x8 sv = *(s16x8*)sp(r, it * 128 + c * 8);
        #pragma unroll
        for (int u = 0; u < 8; ++u) mx = fmaxf(mx, bf2f(sv[u]));
    }
    #pragma unroll
    for (int off = 8; off; off >>= 1) mx = fmaxf(mx, __shfl_xor(mx, off, 16));

    // pass B: e = exp(S - mx), store e (bf16), accumulate sum
    float sum = 0.f;
    #pragma unroll
    for (int it = 0; it < 8; ++it) {
        unsigned short* p = sp(r, it * 128 + c * 8);
        s16x8 sv = *(s16x8*)p;
        s16x8 ev;
        #pragma unroll
        for (int u = 0; u < 8; ++u) {
            float e = __expf(bf2f(sv[u]) - mx);
            sum += e;
            ev[u] = (short)f2bf(e);
        }
        *(s16x8*)p = ev;
    }
    #pragma unroll
    for (int off = 8; off; off >>= 1) sum += __shfl_xor(sum, off, 16);
    float inv = 1.0f / sum;

    // pass C: P = e * inv -> LDS + global attn
    unsigned short* arow = attnw + ((i0 + r) * BH + bh) * NSEQ;
    #pragma unroll
    for (int it = 0; it < 8; ++it) {
        unsigned short* p = sp(r, it * 128 + c * 8);
        s16x8 ev = *(s16x8*)p;
        s16x8 pv;
        #pragma unroll
        for (int u = 0; u < 8; ++u) pv[u] = (short)f2bf(bf2f(ev[u]) * inv);
        *(s16x8*)p = pv;
        *(s16x8*)(arow + it * 128 + c * 8) = pv;
    }
    __syncthreads();

    // ---- phase 3: outv = P @ V ; wave w owns d quarter [w*16, w*16+16) ----
    int d0 = wave * 16;
    const unsigned short* vrow = vtws + (bh * HD + d0 + lr) * NSEQ;
    f32x4 oacc = {0.f, 0.f, 0.f, 0.f};
    for (int kt = 0; kt < 32; ++kt) {
        int jb = kt * 32 + lg * 8;
        s16x8 af = *(const s16x8*)sp(lr, jb);
        s16x8 bf = *(const s16x8*)(vrow + jb);
        oacc = mfma16(af, bf, oacc);
    }
    float* orow = outv + (bh * NSEQ + i0) * HD;
    #pragma unroll
    for (int v = 0; v < 4; ++v)
        orow[(lg * 4 + v) * HD + d0 + lr] = oacc[v];
}

// ---------------------------------------------------------------------------
// K3: per query row i: pes[bh][i][c] = attn[i] (32bh x 1024j) @ pe[i] (1024j x 32c)
// pe staged through double-buffered transposed bf16 LDS tiles [32][136].
// grid (1024), block 256: 4 waves = 2 bh-halves x 2 c-halves.
// ---------------------------------------------------------------------------
__global__ __launch_bounds__(256) void k_pe(
    const unsigned short* __restrict__ attnw, const float* __restrict__ pe,
    float* __restrict__ pes)
{
    __shared__ unsigned short pt[2][PEC][136];   // 17.4 KB
    int i = blockIdx.x;
    int tid = threadIdx.x;
    int lane = tid & 63, wave = tid >> 6;
    int lr = lane & 15, lg = lane >> 4;
    int bh0 = (wave >> 1) * 16;
    int c0  = (wave & 1) * 16;
    const float* pei = pe + (size_t)i * NSEQ * PEC;
    int jp = tid & 63;        // j-pair index (covers 2 consecutive j)
    int cg = tid >> 6;        // c-octet

    auto stage = [&](int buf, int blk) {
        int j = blk * 128 + jp * 2;
        const float* s0 = pei + (size_t)j * PEC + cg * 8;
        f32x4 a0 = *(const f32x4*)(s0);
        f32x4 a1 = *(const f32x4*)(s0 + 4);
        f32x4 b0 = *(const f32x4*)(s0 + PEC);
        f32x4 b1 = *(const f32x4*)(s0 + PEC + 4);
        #pragma unroll
        for (int cc = 0; cc < 4; ++cc) {
            unsigned lo = f2bf(a0[cc]), hi = f2bf(b0[cc]);
            *(unsigned*)&pt[buf][cg * 8 + cc][jp * 2] = lo | (hi << 16);
        }
        #pragma unroll
        for (int cc = 0; cc < 4; ++cc) {
            unsigned lo = f2bf(a1[cc]), hi = f2bf(b1[cc]);
            *(unsigned*)&pt[buf][cg * 8 + 4 + cc][jp * 2] = lo | (hi << 16);
        }
    };

    const unsigned short* arow = attnw + ((size_t)i * BH + bh0 + lr) * NSEQ;
    f32x4 acc = {0.f, 0.f, 0.f, 0.f};

    stage(0, 0);
    __syncthreads();
    for (int blk = 0; blk < 8; ++blk) {
        int cur = blk & 1;
        if (blk < 7) stage(cur ^ 1, blk + 1);
        int j0 = blk * 128;
        #pragma unroll
        for (int kt = 0; kt < 4; ++kt) {
            s16x8 af = *(const s16x8*)(arow + j0 + kt * 32 + lg * 8);
            s16x8 bf = *(const s16x8*)&pt[cur][c0 + lr][kt * 32 + lg * 8];
            acc = mfma16(af, bf, acc);
        }
        __syncthreads();
    }
    #pragma unroll
    for (int v = 0; v < 4; ++v)
        pes[((bh0 + lg * 4 + v) * NSEQ + i) * PEC + c0 + lr] = acc[v];
}

// ---------------------------------------------------------------------------
// K4: t[b][n][h*64+d] = outv + pes @ Wpe^T + bpe   (bf16 packed)
// grid (32, 32), block 256: 32 rows/block, 8 threads/row, 8 d each.
// ---------------------------------------------------------------------------
__global__ __launch_bounds__(256) void k_comb(
    const float* __restrict__ outv, const float* __restrict__ pes,
    const float* __restrict__ Wpe, const float* __restrict__ bpe,
    unsigned short* __restrict__ tws)
{
    __shared__ float wpe_s[HD * PEC];
    __shared__ float bpe_s[HD];
    int tid = threadIdx.x;
    for (int idx = tid; idx < HD * PEC; idx += 256) wpe_s[idx] = Wpe[idx];
    if (tid < HD) bpe_s[tid] = bpe[tid];
    __syncthreads();

    int bh = blockIdx.y;
    int n  = blockIdx.x * 32 + (tid >> 3);
    int d0 = (tid & 7) * 8;
    int b = bh >> 3, h = bh & 7;

    float pr[PEC];
    const float* prow = pes + (bh * NSEQ + n) * PEC;
    #pragma unroll
    for (int c = 0; c < PEC; c += 4) {
        f32x4 t = *(const f32x4*)(prow + c);
        pr[c] = t[0]; pr[c + 1] = t[1]; pr[c + 2] = t[2]; pr[c + 3] = t[3];
    }
    const float* ovp = outv + (bh * NSEQ + n) * HD + d0;
    s16x8 pk;
    #pragma unroll
    for (int dd = 0; dd < 8; ++dd) {
        float acc = bpe_s[d0 + dd] + ovp[dd];
        const float* wrow = &wpe_s[(d0 + dd) * PEC];
        #pragma unroll
        for (int c = 0; c < PEC; ++c) acc += pr[c] * wrow[c];
        pk[dd] = (short)f2bf(acc);
    }
    *(s16x8*)(tws + (b * NSEQ + n) * INNER + h * HD + d0) = pk;
}

// ---------------------------------------------------------------------------
// K5: out[b][n][:] = t @ Wproj^T    (4096 x 128, K=512)
// grid (2, 256), block 256: each wave one 16x16 tile.
// ---------------------------------------------------------------------------
__global__ __launch_bounds__(256) void k_proj(
    const unsigned short* __restrict__ tws, const float* __restrict__ Wproj,
    float* __restrict__ out)
{
    int lane = threadIdx.x & 63, wave = threadIdx.x >> 6;
    int lr = lane & 15, lg = lane >> 4;
    int n0 = (blockIdx.x * 4 + wave) * 16;
    int m0 = blockIdx.y * 16;
    const unsigned short* arow = tws + (m0 + lr) * INNER;
    const float* brow = Wproj + (n0 + lr) * INNER;
    f32x4 acc = {0.f, 0.f, 0.f, 0.f};
    for (int kt = 0; kt < 16; ++kt) {
        s16x8 af = *(const s16x8*)(arow + kt * 32 + lg * 8);
        s16x8 bf = load8bf(brow + kt * 32 + lg * 8);
        acc = mfma16(af, bf, acc);
    }
    #pragma unroll
    for (int v = 0; v < 4; ++v)
        out[(m0 + lg * 4 + v) * DIM + n0 + lr] = acc[v];
}

// ---------------------------------------------------------------------------
// Workspace layout (92 MiB total):
//   [ 0,  4) MiB q_ws   bf16 [bh][n][64]
//   [ 4,  8) MiB k_ws   bf16 [bh][n][64]
//   [ 8, 12) MiB vT_ws  bf16 [bh][64][n]
//   [12, 76) MiB attn   bf16 [i][bh][j]
//   [76, 84) MiB outv   f32  [bh][n][64]
//   [84, 88) MiB pes    f32  [bh][n][32]
//   [88, 92) MiB t      bf16 [b][n][512]
// ---------------------------------------------------------------------------
extern "C" void kernel_launch(void* const* d_in, const int* in_sizes, int n_in,
                              void* d_out, int out_size, void* d_ws, size_t ws_size,
                              hipStream_t stream)
{
    const float* x     = (const float*)d_in[0];
    const float* pe    = (const float*)d_in[1];
    const float* Wq    = (const float*)d_in[2];
    const float* Wk    = (const float*)d_in[3];
    const float* Wv    = (const float*)d_in[4];
    const float* bv    = (const float*)d_in[5];
    const float* Wproj = (const float*)d_in[6];
    const float* Wpe   = (const float*)d_in[7];
    const float* bpe   = (const float*)d_in[8];
    float* out = (float*)d_out;

    char* ws = (char*)d_ws;
    unsigned short* qws  = (unsigned short*)(ws);
    unsigned short* kws  = (unsigned short*)(ws + ( 4u << 20));
    unsigned short* vtws = (unsigned short*)(ws + ( 8u << 20));
    unsigned short* attn = (unsigned short*)(ws + (12u << 20));
    float*          outv = (float*)         (ws + (76u << 20));
    float*          pes  = (float*)         (ws + (84u << 20));
    unsigned short* tws  = (unsigned short*)(ws + (88u << 20));

    k_qkv <<<dim3(24, 256), 256, 0, stream>>>(x, Wq, Wk, Wv, bv, qws, kws, vtws);
    k_attn<<<dim3(64, 32),  256, 0, stream>>>(qws, kws, vtws, attn, outv);
    k_pe  <<<dim3(1024),    256, 0, stream>>>(attn, pe, pes);
    k_comb<<<dim3(32, 32),  256, 0, stream>>>(outv, pes, Wpe, bpe, tws);
    k_proj<<<dim3(2, 256),  256, 0, stream>>>(tws, Wproj, out);
}